// Round 1
// 202.571 us; speedup vs baseline: 1.0598x; 1.0598x over previous
//
#include <hip/hip_runtime.h>

// BioNorm: out = w * x^p / (sigma^p + depthwise_conv5x5(x^p, edge-pad)) + b
// B=32, C=64, H=W=112, K=5, fp32.
//
// V2: register sliding-window over rows + conflict-free LDS reads.
//  - Work is anchored on conv CENTERS (rows/cols 2..109). Edge-padded outputs
//    (rows/cols 0,1,110,111) reuse the clamped center's denominator with the
//    real pixel's numerator (matches reference: pad applies to conv output).
//  - Each lane owns 4 center-columns [4g+2, 4g+5]; its input window is cols
//    [4g, 4g+8) -> two 16B-aligned ds_read_b128 per new row, lane-contiguous
//    stride-16B => canonical conflict-free pattern (old kernel: scalar b32
//    reads, 8-way conflicts, 27.6M conflict cycles = ~50% of runtime).
//  - Sliding 5x8 register window: per output row only ONE new row segment is
//    read from LDS (2 reads vs 11); x^p numerators come from the window.
//  - Block = 128 thr = 4 strips x 32 lanes (27 active); 9 center-rows/strip.
//    grid.x=3 tiles centers [2,109] as 3 x 36 exactly; staged rows 36bx..36bx+39
//    never clamp. LDS 40x116x4 = 18.6KB -> 8 blocks/CU.

#define Cch 64
#define Hh 112
#define Ww 112
#define ST 116            // LDS row stride in floats (keeps rows 16B-aligned, bank-skews rows)
#define SROWS 40          // staged rows per block
#define CPB 36            // center rows per block (grid.x = 3)
#define RPS 9             // center rows per strip (4 strips)

__global__ __launch_bounds__(128) void bionorm_kernel(
    const float* __restrict__ x, const float* __restrict__ sigma,
    const float* __restrict__ pow_p, const float* __restrict__ sum_kernel,
    const float* __restrict__ weight, const float* __restrict__ bias,
    float* __restrict__ out)
{
    __shared__ float lds[SROWS * ST];

    const int bx  = blockIdx.x;   // 0..2 (center-row tile)
    const int c   = blockIdx.y;
    const int b   = blockIdx.z;
    const int tid = threadIdx.x;

    // per-channel params (wave-uniform)
    const float p  = pow_p[c];
    const float sg = sigma[c];
    const float wc = weight[c];
    const float bc = bias[c];
    const bool  p2 = (p == 2.0f);
    const float sp = p2 ? sg * sg : __powf(sg, p);

    float kw[25];
    const float* kp = sum_kernel + c * 25;
    #pragma unroll
    for (int j = 0; j < 25; ++j) kw[j] = kp[j];

    const float* xplane = x + ((size_t)(b * Cch + c)) * (Hh * Ww);
    const int r0 = bx * CPB;      // first staged global row (= cb-2); never clamps

    // ---- stage x^p: 40 rows x 28 float4, fully coalesced ----
    for (int i = tid; i < SROWS * 28; i += 128) {
        int s = i / 28, q = i - s * 28;
        const float4 v = *(const float4*)(xplane + (r0 + s) * Ww + q * 4);
        float4 xp;
        if (p2) {
            xp.x = v.x * v.x; xp.y = v.y * v.y;
            xp.z = v.z * v.z; xp.w = v.w * v.w;
        } else {
            xp.x = __powf(v.x, p); xp.y = __powf(v.y, p);
            xp.z = __powf(v.z, p); xp.w = __powf(v.w, p);
        }
        *(float4*)(&lds[s * ST + q * 4]) = xp;
    }
    __syncthreads();

    const int ss = tid >> 5;      // strip 0..3
    const int g  = tid & 31;      // column group; 27 active
    if (g >= 27) return;          // no further barriers

    const int cs   = 2 + bx * CPB + ss * RPS;  // first center row of this strip
    const int col0 = 4 * g;                    // window col base; centers at col0+2..col0+5
    // lds row of global row rr is rr - r0; strip's first window row (cs-2) -> lds row 9*ss
    const int lbase = (9 * ss) * ST + col0;

    float* oplane = out + ((size_t)(b * Cch + c)) * (Hh * Ww);

    // sliding window: win[m % 5] holds global row (cs - 2 + m), cols [col0, col0+8)
    float win[5][8];

    #define LOADW(SL, KR) { \
        const float4 a_  = *(const float4*)(&lds[lbase + (KR) * ST]);     \
        const float4 b_  = *(const float4*)(&lds[lbase + (KR) * ST + 4]); \
        win[SL][0] = a_.x; win[SL][1] = a_.y; win[SL][2] = a_.z; win[SL][3] = a_.w; \
        win[SL][4] = b_.x; win[SL][5] = b_.y; win[SL][6] = b_.z; win[SL][7] = b_.w; }

    // emit one output row gr using numerator row slot SL and denominators d0..d3
    #define EMITROW(GR, SL) { \
        float* orw_ = oplane + (GR) * Ww; \
        *(float2*)(orw_ + col0 + 2) = make_float2(fmaf(wc * win[SL][2], d0, bc), \
                                                  fmaf(wc * win[SL][3], d1, bc)); \
        *(float2*)(orw_ + col0 + 4) = make_float2(fmaf(wc * win[SL][4], d2, bc), \
                                                  fmaf(wc * win[SL][5], d3, bc)); \
        if (g == 0)  *(float2*)(orw_)       = make_float2(fmaf(wc * win[SL][0], d0, bc), \
                                                          fmaf(wc * win[SL][1], d0, bc)); \
        if (g == 26) *(float2*)(orw_ + 110) = make_float2(fmaf(wc * win[SL][6], d3, bc), \
                                                          fmaf(wc * win[SL][7], d3, bc)); }

    // prologue: rows cs-2 .. cs+1 -> slots 0..3
    LOADW(0, 0) LOADW(1, 1) LOADW(2, 2) LOADW(3, 3)

    #pragma unroll
    for (int k = 0; k < RPS; ++k) {
        LOADW((k + 4) % 5, k + 4)   // new bottom row cs+k+2

        float S0 = 0.f, S1 = 0.f, S2 = 0.f, S3 = 0.f;
        #pragma unroll
        for (int dy = 0; dy < 5; ++dy) {
            const int sl = (k + dy) % 5;   // global row cs+k-2+dy
            #pragma unroll
            for (int dx = 0; dx < 5; ++dx) {
                const float kv = kw[dy * 5 + dx];
                S0 = fmaf(kv, win[sl][dx + 0], S0);
                S1 = fmaf(kv, win[sl][dx + 1], S1);
                S2 = fmaf(kv, win[sl][dx + 2], S2);
                S3 = fmaf(kv, win[sl][dx + 3], S3);
            }
        }

        const float d0 = __builtin_amdgcn_rcpf(sp + S0);
        const float d1 = __builtin_amdgcn_rcpf(sp + S1);
        const float d2 = __builtin_amdgcn_rcpf(sp + S2);
        const float d3 = __builtin_amdgcn_rcpf(sp + S3);

        const int cgl = cs + k;            // center (output) row
        EMITROW(cgl, (k + 2) % 5)          // numerator = center row itself

        if (cgl == 2) {                    // replicate-pad rows 0,1 (denoms of row 2)
            EMITROW(0, (k + 0) % 5)        // numerator row 0
            EMITROW(1, (k + 1) % 5)        // numerator row 1
        }
        if (cgl == 109) {                  // replicate-pad rows 110,111
            EMITROW(110, (k + 3) % 5)      // numerator row 110
            EMITROW(111, (k + 4) % 5)      // numerator row 111
        }
    }
    #undef LOADW
    #undef EMITROW
}

extern "C" void kernel_launch(void* const* d_in, const int* in_sizes, int n_in,
                              void* d_out, int out_size, void* d_ws, size_t ws_size,
                              hipStream_t stream) {
    const float* x          = (const float*)d_in[0];
    const float* sigma      = (const float*)d_in[1];
    const float* pow_p      = (const float*)d_in[2];
    const float* sum_kernel = (const float*)d_in[3];
    const float* weight     = (const float*)d_in[4];
    const float* bias       = (const float*)d_in[5];
    float* out = (float*)d_out;

    dim3 grid(3, Cch, 32);   // (center-row tiles, C, B)
    dim3 block(128);
    bionorm_kernel<<<grid, block, 0, stream>>>(x, sigma, pow_p, sum_kernel,
                                               weight, bias, out);
}

// Round 2
// 199.012 us; speedup vs baseline: 1.0788x; 1.0179x over previous
//
#include <hip/hip_runtime.h>

// BioNorm: out = w * x^p / (sigma^p + depthwise_conv5x5(x^p, edge-pad)) + b
// B=32, C=64, H=W=112, K=5, fp32.
//
// V3: LDS-free register sliding-window.
//  R1 post-mortem: LDS tile killed occupancy (18.6KB -> 16 waves/CU, 33%
//  measured) and added a stage+barrier serial phase; kernel went
//  latency-bound (VALUBusy 32%, HBM 26%). Reads are L3-resident
//  (FETCH 54MB < 102MB input), so the ~2.9x read amplification from
//  dropping LDS reuse is absorbed by L1/L2/L3.
//  - Work anchored on conv CENTERS (rows/cols 2..109); edge-padded outputs
//    reuse the clamped center's denominator with the real pixel numerator.
//  - Lane g (0..26 of 32) owns center cols [4g+2,4g+5]; window cols [4g,4g+8)
//    -> two 16B-aligned global_load_dwordx4 per row, lane-contiguous (second
//    overlaps neighbor's first -> L1 hit).
//  - 5x8 register window slides down 9 center rows; next row prefetched one
//    iteration ahead (fully unrolled -> register rename, no scratch).
//  - Block 128 = 4 strips x 32 lanes; grid (3,64,32); no barriers; occupancy
//    VGPR-limited only.

#define Cch 64
#define Hh 112
#define Ww 112
#define CPB 36            // center rows per block (grid.x = 3)
#define RPS 9             // center rows per strip (4 strips)

__global__ __launch_bounds__(128) void bionorm_kernel(
    const float* __restrict__ x, const float* __restrict__ sigma,
    const float* __restrict__ pow_p, const float* __restrict__ sum_kernel,
    const float* __restrict__ weight, const float* __restrict__ bias,
    float* __restrict__ out)
{
    const int bx  = blockIdx.x;   // 0..2 (center-row tile)
    const int c   = blockIdx.y;
    const int b   = blockIdx.z;
    const int tid = threadIdx.x;

    const int ss = tid >> 5;      // strip 0..3
    const int g  = tid & 31;      // column group; 27 active
    if (g >= 27) return;

    // per-channel params (wave-uniform -> scalar loads)
    const float p  = pow_p[c];
    const float sg = sigma[c];
    const float wc = weight[c];
    const float bc = bias[c];
    const bool  p2 = (p == 2.0f);
    const float sp = p2 ? sg * sg : __powf(sg, p);

    float kw[25];
    const float* kp = sum_kernel + c * 25;
    #pragma unroll
    for (int j = 0; j < 25; ++j) kw[j] = kp[j];

    const float* xplane = x + ((size_t)(b * Cch + c)) * (Hh * Ww);
    float* oplane = out + ((size_t)(b * Cch + c)) * (Hh * Ww);

    const int cs   = 2 + bx * CPB + ss * RPS;  // first center row of this strip
    const int col0 = 4 * g;                    // window col base

    // sliding window: win[(r-(cs-2)) % 5] holds x^p of global row r, cols [col0,col0+8)
    float win[5][8];

    #define CVT8(SL, VA, VB) { \
        if (p2) { \
            win[SL][0] = VA.x * VA.x; win[SL][1] = VA.y * VA.y; \
            win[SL][2] = VA.z * VA.z; win[SL][3] = VA.w * VA.w; \
            win[SL][4] = VB.x * VB.x; win[SL][5] = VB.y * VB.y; \
            win[SL][6] = VB.z * VB.z; win[SL][7] = VB.w * VB.w; \
        } else { \
            win[SL][0] = __powf(VA.x, p); win[SL][1] = __powf(VA.y, p); \
            win[SL][2] = __powf(VA.z, p); win[SL][3] = __powf(VA.w, p); \
            win[SL][4] = __powf(VB.x, p); win[SL][5] = __powf(VB.y, p); \
            win[SL][6] = __powf(VB.z, p); win[SL][7] = __powf(VB.w, p); \
        } }

    // emit one output row GR: numerator from window slot SL, denominators d0..d3
    #define EMITROW(GR, SL) { \
        float* orw_ = oplane + (GR) * Ww; \
        *(float2*)(orw_ + col0 + 2) = make_float2(fmaf(wc * win[SL][2], d0, bc), \
                                                  fmaf(wc * win[SL][3], d1, bc)); \
        *(float2*)(orw_ + col0 + 4) = make_float2(fmaf(wc * win[SL][4], d2, bc), \
                                                  fmaf(wc * win[SL][5], d3, bc)); \
        if (g == 0)  *(float2*)(orw_)       = make_float2(fmaf(wc * win[SL][0], d0, bc), \
                                                          fmaf(wc * win[SL][1], d0, bc)); \
        if (g == 26) *(float2*)(orw_ + 110) = make_float2(fmaf(wc * win[SL][6], d3, bc), \
                                                          fmaf(wc * win[SL][7], d3, bc)); }

    // ---- prologue: rows cs-2 .. cs+1 -> slots 0..3; prefetch row cs+2 ----
    {
        const float4 a0 = *(const float4*)(xplane + (cs - 2) * Ww + col0);
        const float4 b0 = *(const float4*)(xplane + (cs - 2) * Ww + col0 + 4);
        const float4 a1 = *(const float4*)(xplane + (cs - 1) * Ww + col0);
        const float4 b1 = *(const float4*)(xplane + (cs - 1) * Ww + col0 + 4);
        const float4 a2 = *(const float4*)(xplane + (cs    ) * Ww + col0);
        const float4 b2 = *(const float4*)(xplane + (cs    ) * Ww + col0 + 4);
        const float4 a3 = *(const float4*)(xplane + (cs + 1) * Ww + col0);
        const float4 b3 = *(const float4*)(xplane + (cs + 1) * Ww + col0 + 4);
        CVT8(0, a0, b0) CVT8(1, a1, b1) CVT8(2, a2, b2) CVT8(3, a3, b3)
    }
    float4 A0 = *(const float4*)(xplane + (cs + 2) * Ww + col0);
    float4 A1 = *(const float4*)(xplane + (cs + 2) * Ww + col0 + 4);

    #pragma unroll
    for (int k = 0; k < RPS; ++k) {
        // prefetch row cs+k+3 (clamped; last iter's fetch is redundant-but-safe)
        const int nr  = cs + k + 3;
        const int nrc = nr > 111 ? 111 : nr;
        const float4 B0 = *(const float4*)(xplane + nrc * Ww + col0);
        const float4 B1 = *(const float4*)(xplane + nrc * Ww + col0 + 4);

        // convert last-prefetched row cs+k+2 into slot (k+4)%5
        CVT8((k + 4) % 5, A0, A1)

        float S0 = 0.f, S1 = 0.f, S2 = 0.f, S3 = 0.f;
        #pragma unroll
        for (int dy = 0; dy < 5; ++dy) {
            const int sl = (k + dy) % 5;   // global row cs+k-2+dy
            #pragma unroll
            for (int dx = 0; dx < 5; ++dx) {
                const float kv = kw[dy * 5 + dx];
                S0 = fmaf(kv, win[sl][dx + 0], S0);
                S1 = fmaf(kv, win[sl][dx + 1], S1);
                S2 = fmaf(kv, win[sl][dx + 2], S2);
                S3 = fmaf(kv, win[sl][dx + 3], S3);
            }
        }

        const float d0 = __builtin_amdgcn_rcpf(sp + S0);
        const float d1 = __builtin_amdgcn_rcpf(sp + S1);
        const float d2 = __builtin_amdgcn_rcpf(sp + S2);
        const float d3 = __builtin_amdgcn_rcpf(sp + S3);

        const int cgl = cs + k;            // center (output) row
        EMITROW(cgl, (k + 2) % 5)

        if (k == 0 && cs == 2) {           // replicate-pad rows 0,1
            EMITROW(0, 0)                  // numerator row 0 (slot 0)
            EMITROW(1, 1)                  // numerator row 1 (slot 1)
        }
        if (k == RPS - 1 && cgl == 109) {  // replicate-pad rows 110,111
            EMITROW(110, (k + 3) % 5)      // numerator row 110
            EMITROW(111, (k + 4) % 5)      // numerator row 111
        }

        A0 = B0; A1 = B1;
    }
    #undef CVT8
    #undef EMITROW
}

extern "C" void kernel_launch(void* const* d_in, const int* in_sizes, int n_in,
                              void* d_out, int out_size, void* d_ws, size_t ws_size,
                              hipStream_t stream) {
    const float* x          = (const float*)d_in[0];
    const float* sigma      = (const float*)d_in[1];
    const float* pow_p      = (const float*)d_in[2];
    const float* sum_kernel = (const float*)d_in[3];
    const float* weight     = (const float*)d_in[4];
    const float* bias       = (const float*)d_in[5];
    float* out = (float*)d_out;

    dim3 grid(3, Cch, 32);   // (center-row tiles, C, B)
    dim3 block(128);
    bionorm_kernel<<<grid, block, 0, stream>>>(x, sigma, pow_p, sum_kernel,
                                               weight, bias, out);
}